// Round 1
// baseline (2332.284 us; speedup 1.0000x reference)
//
#include <hip/hip_runtime.h>

#define ND 64

__device__ __forceinline__ float lrelu(float x) { return x > 0.f ? x : 0.2f * x; }

// monotonic float -> uint encoding for atomicMax
__device__ __forceinline__ unsigned enc(float f) {
    unsigned u = __float_as_uint(f);
    return (u & 0x80000000u) ? ~u : (u | 0x80000000u);
}
__device__ __forceinline__ float dec(unsigned u) {
    return __uint_as_float((u & 0x80000000u) ? (u & 0x7fffffffu) : ~u);
}

__device__ __forceinline__ float wave_sum(float v) {
#pragma unroll
    for (int m = 32; m > 0; m >>= 1) v += __shfl_xor(v, m, 64);
    return v;
}

// h = x @ W ; ssrc = h . a_src ; sdst = h . a_dst   (one wave per node)
__global__ void gemm_scores(const float* __restrict__ x, const float* __restrict__ W,
                            const float* __restrict__ asrc, const float* __restrict__ adst,
                            float* __restrict__ h, float* __restrict__ ssrc,
                            float* __restrict__ sdst, int n) {
    int wave = threadIdx.x >> 6;
    int lane = threadIdx.x & 63;
    int node = blockIdx.x * 4 + wave;
    __shared__ float xs[4][ND];
    if (node < n) xs[wave][lane] = x[node * ND + lane];
    __syncthreads();
    if (node >= n) return;
    float acc = 0.f;
#pragma unroll
    for (int k = 0; k < ND; k++) acc = fmaf(xs[wave][k], W[k * ND + lane], acc);
    h[node * ND + lane] = acc;
    float s1 = wave_sum(acc * asrc[lane]);
    float s2 = wave_sum(acc * adst[lane]);
    if (lane == 0) { ssrc[node] = s1; sdst[node] = s2; }
}

// init segment max with the self-loop edge value (every node has one)
__global__ void self_init(const float* __restrict__ ssrc, const float* __restrict__ sdst,
                          unsigned* __restrict__ menc, int n) {
    int i = blockIdx.x * blockDim.x + threadIdx.x;
    if (i < n) menc[i] = enc(lrelu(ssrc[i] + sdst[i]));
}

__global__ void edge_max(const int* __restrict__ ei, const float* __restrict__ ssrc,
                         const float* __restrict__ sdst, unsigned* __restrict__ menc, int E) {
    int e = blockIdx.x * blockDim.x + threadIdx.x;
    if (e >= E) return;
    int s = ei[e], d = ei[E + e];
    atomicMax(&menc[d], enc(lrelu(ssrc[s] + sdst[d])));
}

// decode max, seed denom/acc with the self-loop contribution
__global__ void decode_init(const float* __restrict__ h, const float* __restrict__ ssrc,
                            const float* __restrict__ sdst, const unsigned* __restrict__ menc,
                            float* __restrict__ m, float* __restrict__ denom,
                            float* __restrict__ acc, int n) {
    int gid = blockIdx.x * blockDim.x + threadIdx.x;
    int node = gid >> 6, lane = gid & 63;
    if (node >= n) return;
    float mv = dec(menc[node]);
    float wv = expf(lrelu(ssrc[node] + sdst[node]) - mv);
    acc[node * ND + lane] = wv * h[node * ND + lane];
    if (lane == 0) { m[node] = mv; denom[node] = wv; }
}

// one wave per edge: lane j accumulates column j of w * h[src] into acc[dst]
__global__ void edge_accum(const int* __restrict__ ei, const float* __restrict__ ssrc,
                           const float* __restrict__ sdst, const float* __restrict__ m,
                           const float* __restrict__ h, float* __restrict__ acc,
                           float* __restrict__ denom, int E) {
    long long gid = (long long)blockIdx.x * blockDim.x + threadIdx.x;
    int e = (int)(gid >> 6), lane = (int)(gid & 63);
    if (e >= E) return;
    int s = ei[e], d = ei[E + e];
    float w = expf(lrelu(ssrc[s] + sdst[d]) - m[d]);
    atomicAdd(&acc[d * ND + lane], w * h[s * ND + lane]);
    if (lane == 0) atomicAdd(&denom[d], w);
}

__global__ void finalize(float* __restrict__ acc, const float* __restrict__ denom,
                         const float* __restrict__ bias, int n, int relu) {
    int gid = blockIdx.x * blockDim.x + threadIdx.x;
    int node = gid >> 6, lane = gid & 63;
    if (node >= n) return;
    float v = acc[gid] / denom[node] + bias[lane];
    if (relu) v = fmaxf(v, 0.f);
    acc[gid] = v;
}

// branch attention: fused = softmax2(att0.hi, att1.hp) blend   (one wave per node)
__global__ void branch_att(const float* __restrict__ hi, const float* __restrict__ hp,
                           const float* __restrict__ att, float* __restrict__ fused, int n) {
    int gid = blockIdx.x * blockDim.x + threadIdx.x;
    int node = gid >> 6, lane = gid & 63;
    if (node >= n) return;
    float vi = hi[node * ND + lane], vp = hp[node * ND + lane];
    float s0 = wave_sum(att[lane] * vi);
    float s1 = wave_sum(att[ND + lane] * vp);
    float mx = fmaxf(s0, s1);
    float a0 = expf(s0 - mx), a1 = expf(s1 - mx);
    fused[node * ND + lane] = (a0 * vi + a1 * vp) / (a0 + a1);
}

// branch attention + final 64->1 MLP
__global__ void branch_att_mlp(const float* __restrict__ gi, const float* __restrict__ gp,
                               const float* __restrict__ att, const float* __restrict__ mlpw,
                               const float* __restrict__ mlpb, float* __restrict__ out, int n) {
    int gid = blockIdx.x * blockDim.x + threadIdx.x;
    int node = gid >> 6, lane = gid & 63;
    if (node >= n) return;
    float vi = gi[node * ND + lane], vp = gp[node * ND + lane];
    float s0 = wave_sum(att[lane] * vi);
    float s1 = wave_sum(att[ND + lane] * vp);
    float mx = fmaxf(s0, s1);
    float a0 = expf(s0 - mx), a1 = expf(s1 - mx);
    float xj = (a0 * vi + a1 * vp) / (a0 + a1);
    float o = wave_sum(xj * mlpw[lane]);
    if (lane == 0) out[node] = o + mlpb[0];
}

extern "C" void kernel_launch(void* const* d_in, const int* in_sizes, int n_in,
                              void* d_out, int out_size, void* d_ws, size_t ws_size,
                              hipStream_t stream) {
    const int N = in_sizes[0] / ND;   // 50000
    const int E = in_sizes[2] / 2;    // 1600000

    const float* x_ind = (const float*)d_in[0];
    const float* x_pos = (const float*)d_in[1];
    const int*   e_ind = (const int*)d_in[2];
    const int*   e_pos = (const int*)d_in[3];
    const float* w1i = (const float*)d_in[4];
    const float* as1i = (const float*)d_in[5];
    const float* ad1i = (const float*)d_in[6];
    const float* b1i = (const float*)d_in[7];
    const float* w2i = (const float*)d_in[8];
    const float* as2i = (const float*)d_in[9];
    const float* ad2i = (const float*)d_in[10];
    const float* b2i = (const float*)d_in[11];
    const float* w1p = (const float*)d_in[12];
    const float* as1p = (const float*)d_in[13];
    const float* ad1p = (const float*)d_in[14];
    const float* b1p = (const float*)d_in[15];
    const float* w2p = (const float*)d_in[16];
    const float* as2p = (const float*)d_in[17];
    const float* ad2p = (const float*)d_in[18];
    const float* b2p = (const float*)d_in[19];
    const float* fha = (const float*)d_in[20];
    const float* attw = (const float*)d_in[21];
    const float* mlpw = (const float*)d_in[22];
    const float* mlpb = (const float*)d_in[23];

    float* ws = (float*)d_ws;
    size_t off = 0;
    float* htmp = ws + off; off += (size_t)N * ND;
    float* bufA = ws + off; off += (size_t)N * ND;   // h_i, then g_i
    float* bufB = ws + off; off += (size_t)N * ND;   // h_p, then g_p
    float* bufC = ws + off; off += (size_t)N * ND;   // fused
    float* ssrc = ws + off; off += N;
    float* sdst = ws + off; off += N;
    float* mbuf = ws + off; off += N;
    float* denom = ws + off; off += N;
    unsigned* menc = (unsigned*)(ws + off); off += N;

    const int nodeBlocks = (N + 3) / 4;              // 4 waves/block, 1 node/wave
    const int elemBlocks = (N * ND + 255) / 256;
    const int edgeBlocks = (E + 255) / 256;
    const long long accThreads = (long long)E * ND;
    const int accBlocks = (int)((accThreads + 255) / 256);

    auto conv = [&](const float* x, const int* ei, const float* W, const float* as,
                    const float* ad, const float* b, float* out, int relu) {
        gemm_scores<<<nodeBlocks, 256, 0, stream>>>(x, W, as, ad, htmp, ssrc, sdst, N);
        self_init<<<(N + 255) / 256, 256, 0, stream>>>(ssrc, sdst, menc, N);
        edge_max<<<edgeBlocks, 256, 0, stream>>>(ei, ssrc, sdst, menc, E);
        decode_init<<<elemBlocks, 256, 0, stream>>>(htmp, ssrc, sdst, menc, mbuf, denom, out, N);
        edge_accum<<<accBlocks, 256, 0, stream>>>(ei, ssrc, sdst, mbuf, htmp, out, denom, E);
        finalize<<<elemBlocks, 256, 0, stream>>>(out, denom, b, N, relu);
    };

    conv(x_ind, e_ind, w1i, as1i, ad1i, b1i, bufA, 1);
    conv(x_pos, e_pos, w1p, as1p, ad1p, b1p, bufB, 1);
    branch_att<<<nodeBlocks, 256, 0, stream>>>(bufA, bufB, fha, bufC, N);
    conv(bufC, e_ind, w2i, as2i, ad2i, b2i, bufA, 0);
    conv(bufC, e_pos, w2p, as2p, ad2p, b2p, bufB, 0);
    branch_att_mlp<<<nodeBlocks, 256, 0, stream>>>(bufA, bufB, attw, mlpw, mlpb,
                                                   (float*)d_out, N);
}

// Round 2
// 1003.062 us; speedup vs baseline: 2.3252x; 2.3252x over previous
//
#include <hip/hip_runtime.h>

#define ND 64
#define SCAN_BS 256

__device__ __forceinline__ float lrelu(float x) { return x > 0.f ? x : 0.2f * x; }

__device__ __forceinline__ float wave_sum(float v) {
#pragma unroll
    for (int m = 32; m > 0; m >>= 1) v += __shfl_xor(v, m, 64);
    return v;
}
__device__ __forceinline__ float wave_max(float v) {
#pragma unroll
    for (int m = 32; m > 0; m >>= 1) v = fmaxf(v, __shfl_xor(v, m, 64));
    return v;
}

// ---------------- CSR build ----------------
__global__ void hist(const int* __restrict__ ei, int* __restrict__ deg, int E) {
    int e = blockIdx.x * blockDim.x + threadIdx.x;
    if (e < E) atomicAdd(&deg[ei[E + e]], 1);
}

// per-block exclusive scan of deg -> row_start(local); block totals -> psum
__global__ void scan_blocks(const int* __restrict__ deg, int* __restrict__ row_start,
                            int* __restrict__ psum, int n) {
    __shared__ int tmp[SCAN_BS];
    int t = threadIdx.x;
    int i = blockIdx.x * SCAN_BS + t;
    int v = (i < n) ? deg[i] : 0;
    tmp[t] = v;
    __syncthreads();
    for (int off = 1; off < SCAN_BS; off <<= 1) {
        int add = (t >= off) ? tmp[t - off] : 0;
        __syncthreads();
        tmp[t] += add;
        __syncthreads();
    }
    if (i < n) row_start[i] = tmp[t] - v;          // exclusive
    if (t == SCAN_BS - 1) psum[blockIdx.x] = tmp[t];
}

// single-block exclusive scan of block totals (nb <= 1024)
__global__ void scan_psum(int* __restrict__ psum, int nb) {
    __shared__ int tmp[1024];
    int t = threadIdx.x;
    int v = (t < nb) ? psum[t] : 0;
    tmp[t] = v;
    __syncthreads();
    for (int off = 1; off < 1024; off <<= 1) {
        int add = (t >= off) ? tmp[t - off] : 0;
        __syncthreads();
        tmp[t] += add;
        __syncthreads();
    }
    if (t < nb) psum[t] = tmp[t] - v;              // exclusive
}

__global__ void scan_add(int* __restrict__ row_start, const int* __restrict__ psum, int n) {
    int i = blockIdx.x * SCAN_BS + threadIdx.x;
    if (i < n) row_start[i] += psum[blockIdx.x];
}

__global__ void scatter(const int* __restrict__ ei, const int* __restrict__ row_start,
                        int* __restrict__ cursor, int* __restrict__ csr, int E) {
    int e = blockIdx.x * blockDim.x + threadIdx.x;
    if (e >= E) return;
    int s = ei[e], d = ei[E + e];
    int p = atomicAdd(&cursor[d], 1);
    csr[row_start[d] + p] = s;
}

// ---------------- per-conv kernels ----------------
// h = x @ W ; ssrc = h . a_src ; sdst = h . a_dst   (one wave per node)
__global__ void gemm_scores(const float* __restrict__ x, const float* __restrict__ W,
                            const float* __restrict__ asrc, const float* __restrict__ adst,
                            float* __restrict__ h, float* __restrict__ ssrc,
                            float* __restrict__ sdst, int n) {
    int wave = threadIdx.x >> 6;
    int lane = threadIdx.x & 63;
    int node = blockIdx.x * 4 + wave;
    __shared__ float xs[4][ND];
    if (node < n) xs[wave][lane] = x[node * ND + lane];
    __syncthreads();
    if (node >= n) return;
    float acc = 0.f;
#pragma unroll
    for (int k = 0; k < ND; k++) acc = fmaf(xs[wave][k], W[k * ND + lane], acc);
    h[node * ND + lane] = acc;
    float s1 = wave_sum(acc * asrc[lane]);
    float s2 = wave_sum(acc * adst[lane]);
    if (lane == 0) { ssrc[node] = s1; sdst[node] = s2; }
}

// one wave per dst node: segment max + edge softmax + weighted gather, no atomics
__global__ void aggregate(const int* __restrict__ csr, const int* __restrict__ row_start,
                          const int* __restrict__ deg, const float* __restrict__ ssrc,
                          const float* __restrict__ sdst, const float* __restrict__ h,
                          const float* __restrict__ bias, float* __restrict__ out,
                          int n, int relu) {
    int wave = threadIdx.x >> 6;
    int lane = threadIdx.x & 63;
    int node = blockIdx.x * 4 + wave;
    if (node >= n) return;

    int start = row_start[node];
    int end = start + deg[node];
    float sd = sdst[node];
    float selfs = lrelu(ssrc[node] + sd);

    // pass 1: segment max (self-loop included)
    float mx = selfs;
    for (int j = start + lane; j < end; j += 64)
        mx = fmaxf(mx, lrelu(ssrc[csr[j]] + sd));
    mx = wave_max(mx);

    // pass 2: softmax-weighted accumulation
    float wself = __expf(selfs - mx);
    float acc = wself * h[node * ND + lane];
    float denom = wself;
    for (int base = start; base < end; base += 64) {
        int cnt = min(64, end - base);
        int sj = (lane < cnt) ? csr[base + lane] : 0;
        float wj = (lane < cnt) ? __expf(lrelu(ssrc[sj] + sd) - mx) : 0.f;
        for (int k = 0; k < cnt; k++) {
            float w = __shfl(wj, k, 64);
            int s = __shfl(sj, k, 64);
            acc = fmaf(w, h[s * ND + lane], acc);
            denom += w;
        }
    }
    float v = acc / denom + bias[lane];
    if (relu) v = fmaxf(v, 0.f);
    out[node * ND + lane] = v;
}

// branch attention: fused = softmax2(att0.hi, att1.hp) blend   (one wave per node)
__global__ void branch_att(const float* __restrict__ hi, const float* __restrict__ hp,
                           const float* __restrict__ att, float* __restrict__ fused, int n) {
    int gid = blockIdx.x * blockDim.x + threadIdx.x;
    int node = gid >> 6, lane = gid & 63;
    if (node >= n) return;
    float vi = hi[node * ND + lane], vp = hp[node * ND + lane];
    float s0 = wave_sum(att[lane] * vi);
    float s1 = wave_sum(att[ND + lane] * vp);
    float m = fmaxf(s0, s1);
    float a0 = __expf(s0 - m), a1 = __expf(s1 - m);
    fused[node * ND + lane] = (a0 * vi + a1 * vp) / (a0 + a1);
}

// branch attention + final 64->1 MLP
__global__ void branch_att_mlp(const float* __restrict__ gi, const float* __restrict__ gp,
                               const float* __restrict__ att, const float* __restrict__ mlpw,
                               const float* __restrict__ mlpb, float* __restrict__ out, int n) {
    int gid = blockIdx.x * blockDim.x + threadIdx.x;
    int node = gid >> 6, lane = gid & 63;
    if (node >= n) return;
    float vi = gi[node * ND + lane], vp = gp[node * ND + lane];
    float s0 = wave_sum(att[lane] * vi);
    float s1 = wave_sum(att[ND + lane] * vp);
    float m = fmaxf(s0, s1);
    float a0 = __expf(s0 - m), a1 = __expf(s1 - m);
    float xj = (a0 * vi + a1 * vp) / (a0 + a1);
    float o = wave_sum(xj * mlpw[lane]);
    if (lane == 0) out[node] = o + mlpb[0];
}

extern "C" void kernel_launch(void* const* d_in, const int* in_sizes, int n_in,
                              void* d_out, int out_size, void* d_ws, size_t ws_size,
                              hipStream_t stream) {
    const int N = in_sizes[0] / ND;   // 50000
    const int E = in_sizes[2] / 2;    // 1600000

    const float* x_ind = (const float*)d_in[0];
    const float* x_pos = (const float*)d_in[1];
    const int*   e_ind = (const int*)d_in[2];
    const int*   e_pos = (const int*)d_in[3];
    const float* w1i = (const float*)d_in[4];
    const float* as1i = (const float*)d_in[5];
    const float* ad1i = (const float*)d_in[6];
    const float* b1i = (const float*)d_in[7];
    const float* w2i = (const float*)d_in[8];
    const float* as2i = (const float*)d_in[9];
    const float* ad2i = (const float*)d_in[10];
    const float* b2i = (const float*)d_in[11];
    const float* w1p = (const float*)d_in[12];
    const float* as1p = (const float*)d_in[13];
    const float* ad1p = (const float*)d_in[14];
    const float* b1p = (const float*)d_in[15];
    const float* w2p = (const float*)d_in[16];
    const float* as2p = (const float*)d_in[17];
    const float* ad2p = (const float*)d_in[18];
    const float* b2p = (const float*)d_in[19];
    const float* fha = (const float*)d_in[20];
    const float* attw = (const float*)d_in[21];
    const float* mlpw = (const float*)d_in[22];
    const float* mlpb = (const float*)d_in[23];

    char* ws = (char*)d_ws;
    size_t off = 0;
    auto alloc = [&](size_t elems) { void* p = ws + off; off += elems * 4; return p; };

    float* htmp = (float*)alloc((size_t)N * ND);
    float* bufA = (float*)alloc((size_t)N * ND);   // h_i then g_i
    float* bufB = (float*)alloc((size_t)N * ND);   // h_p then g_p
    float* bufC = (float*)alloc((size_t)N * ND);   // fused
    float* ssrc = (float*)alloc(N);
    float* sdst = (float*)alloc(N);
    int* degI = (int*)alloc(N);
    int* rowI = (int*)alloc(N);
    int* csrI = (int*)alloc(E);
    int* degP = (int*)alloc(N);
    int* rowP = (int*)alloc(N);
    int* csrP = (int*)alloc(E);
    int* cursor = (int*)alloc(N);
    int* psum = (int*)alloc(1024);

    const int nodeBlocks = (N + 3) / 4;
    const int edgeBlocks = (E + 255) / 256;
    const int nScanBlocks = (N + SCAN_BS - 1) / SCAN_BS;   // 196

    // ---- CSR build for both graphs ----
    auto build_csr = [&](const int* ei, int* deg, int* row, int* csr) {
        hipMemsetAsync(deg, 0, (size_t)N * 4, stream);
        hipMemsetAsync(cursor, 0, (size_t)N * 4, stream);
        hist<<<edgeBlocks, 256, 0, stream>>>(ei, deg, E);
        scan_blocks<<<nScanBlocks, SCAN_BS, 0, stream>>>(deg, row, psum, N);
        scan_psum<<<1, 1024, 0, stream>>>(psum, nScanBlocks);
        scan_add<<<nScanBlocks, SCAN_BS, 0, stream>>>(row, psum, N);
        scatter<<<edgeBlocks, 256, 0, stream>>>(ei, row, cursor, csr, E);
    };
    build_csr(e_ind, degI, rowI, csrI);
    build_csr(e_pos, degP, rowP, csrP);

    auto conv = [&](const float* x, const int* csr, const int* row, const int* deg,
                    const float* W, const float* as, const float* ad, const float* b,
                    float* out, int relu) {
        gemm_scores<<<nodeBlocks, 256, 0, stream>>>(x, W, as, ad, htmp, ssrc, sdst, N);
        aggregate<<<nodeBlocks, 256, 0, stream>>>(csr, row, deg, ssrc, sdst, htmp, b,
                                                  out, N, relu);
    };

    conv(x_ind, csrI, rowI, degI, w1i, as1i, ad1i, b1i, bufA, 1);
    conv(x_pos, csrP, rowP, degP, w1p, as1p, ad1p, b1p, bufB, 1);
    branch_att<<<nodeBlocks, 256, 0, stream>>>(bufA, bufB, fha, bufC, N);
    conv(bufC, csrI, rowI, degI, w2i, as2i, ad2i, b2i, bufA, 0);
    conv(bufC, csrP, rowP, degP, w2p, as2p, ad2p, b2p, bufB, 0);
    branch_att_mlp<<<nodeBlocks, 256, 0, stream>>>(bufA, bufB, attw, mlpw, mlpb,
                                                   (float*)d_out, N);
}

// Round 3
// 868.004 us; speedup vs baseline: 2.6870x; 1.1556x over previous
//
#include <hip/hip_runtime.h>

#define ND 64
#define SCAN_BS 256

__device__ __forceinline__ float lrelu(float x) { return x > 0.f ? x : 0.2f * x; }

__device__ __forceinline__ float wave_sum(float v) {
#pragma unroll
    for (int m = 32; m > 0; m >>= 1) v += __shfl_xor(v, m, 64);
    return v;
}
__device__ __forceinline__ float wave_max(float v) {
#pragma unroll
    for (int m = 32; m > 0; m >>= 1) v = fmaxf(v, __shfl_xor(v, m, 64));
    return v;
}

// ---------------- CSR build (both graphs in one pass) ----------------
// deg[0..N) = graph I, deg[N..2N) = graph P; csr[2E] holds both, row offsets absolute.
__global__ void hist2(const int* __restrict__ eI, const int* __restrict__ eP,
                      int* __restrict__ deg, int N, int E) {
    int e = blockIdx.x * blockDim.x + threadIdx.x;
    if (e < E) atomicAdd(&deg[eI[E + e]], 1);
    else if (e < 2 * E) atomicAdd(&deg[N + eP[E + (e - E)]], 1);
}

__global__ void scan_blocks(const int* __restrict__ deg, int* __restrict__ row,
                            int* __restrict__ psum, int n2) {
    __shared__ int tmp[SCAN_BS];
    int t = threadIdx.x;
    int i = blockIdx.x * SCAN_BS + t;
    int v = (i < n2) ? deg[i] : 0;
    tmp[t] = v;
    __syncthreads();
    for (int off = 1; off < SCAN_BS; off <<= 1) {
        int add = (t >= off) ? tmp[t - off] : 0;
        __syncthreads();
        tmp[t] += add;
        __syncthreads();
    }
    if (i < n2) row[i] = tmp[t] - v;               // exclusive
    if (t == SCAN_BS - 1) psum[blockIdx.x] = tmp[t];
}

__global__ void scan_psum(int* __restrict__ psum, int nb) {
    __shared__ int tmp[1024];
    int t = threadIdx.x;
    int v = (t < nb) ? psum[t] : 0;
    tmp[t] = v;
    __syncthreads();
    for (int off = 1; off < 1024; off <<= 1) {
        int add = (t >= off) ? tmp[t - off] : 0;
        __syncthreads();
        tmp[t] += add;
        __syncthreads();
    }
    if (t < nb) psum[t] = tmp[t] - v;              // exclusive
}

// row += block prefix; also init cursor = row (absolute write positions)
__global__ void scan_add(int* __restrict__ row, int* __restrict__ cursor,
                         const int* __restrict__ psum, int n2) {
    int i = blockIdx.x * SCAN_BS + threadIdx.x;
    if (i < n2) {
        int r = row[i] + psum[blockIdx.x];
        row[i] = r;
        cursor[i] = r;
    }
}

__global__ void scatter2(const int* __restrict__ eI, const int* __restrict__ eP,
                         int* __restrict__ cursor, int* __restrict__ csr, int N, int E) {
    int e = blockIdx.x * blockDim.x + threadIdx.x;
    int s, idx;
    if (e < E) { s = eI[e]; idx = eI[E + e]; }
    else if (e < 2 * E) { s = eP[e - E]; idx = N + eP[E + (e - E)]; }
    else return;
    int p = atomicAdd(&cursor[idx], 1);
    csr[p] = s;
}

// ---------------- h = x @ W + score dots: 4 nodes per wave ----------------
__global__ void gemm_scores(const float* __restrict__ x, const float* __restrict__ W,
                            const float* __restrict__ asrc, const float* __restrict__ adst,
                            float* __restrict__ h, float* __restrict__ ssrc,
                            float* __restrict__ sdst, int n) {
    int wave = threadIdx.x >> 6;
    int lane = threadIdx.x & 63;
    int nodeBase = (blockIdx.x * 4 + wave) * 4;
    __shared__ float xs[4][4 * ND];                // [wave][node*64+k]

    // stage 4 rows (256 floats) per wave via float4
    if (nodeBase + 3 < n) {
        *(float4*)&xs[wave][lane * 4] = *(const float4*)&x[(size_t)nodeBase * ND + lane * 4];
    } else {
#pragma unroll
        for (int i = 0; i < 4; i++) {
            int gi = nodeBase * ND + lane * 4 + i;
            xs[wave][lane * 4 + i] = (gi < n * ND) ? x[gi] : 0.f;
        }
    }
    __syncthreads();
    if (nodeBase >= n) return;

    float4 acc = {0.f, 0.f, 0.f, 0.f};
#pragma unroll
    for (int k = 0; k < ND; k++) {
        float wv = W[k * ND + lane];
        acc.x = fmaf(xs[wave][0 * ND + k], wv, acc.x);
        acc.y = fmaf(xs[wave][1 * ND + k], wv, acc.y);
        acc.z = fmaf(xs[wave][2 * ND + k], wv, acc.z);
        acc.w = fmaf(xs[wave][3 * ND + k], wv, acc.w);
    }
    float av = asrc[lane], dv = adst[lane];
    float s1x = wave_sum(acc.x * av), s2x = wave_sum(acc.x * dv);
    float s1y = wave_sum(acc.y * av), s2y = wave_sum(acc.y * dv);
    float s1z = wave_sum(acc.z * av), s2z = wave_sum(acc.z * dv);
    float s1w = wave_sum(acc.w * av), s2w = wave_sum(acc.w * dv);

    h[(size_t)(nodeBase + 0) * ND + lane] = acc.x;
    if (nodeBase + 1 < n) h[(size_t)(nodeBase + 1) * ND + lane] = acc.y;
    if (nodeBase + 2 < n) h[(size_t)(nodeBase + 2) * ND + lane] = acc.z;
    if (nodeBase + 3 < n) h[(size_t)(nodeBase + 3) * ND + lane] = acc.w;
    if (lane == 0) {
        ssrc[nodeBase] = s1x; sdst[nodeBase] = s2x;
        if (nodeBase + 1 < n) { ssrc[nodeBase + 1] = s1y; sdst[nodeBase + 1] = s2y; }
        if (nodeBase + 2 < n) { ssrc[nodeBase + 2] = s1z; sdst[nodeBase + 2] = s2z; }
        if (nodeBase + 3 < n) { ssrc[nodeBase + 3] = s1w; sdst[nodeBase + 3] = s2w; }
    }
}

// ---------------- aggregate: one wave per dst, 4-row float4 gathers ----------------
__global__ void aggregate(const int* __restrict__ csr, const int* __restrict__ row,
                          const int* __restrict__ deg, const float* __restrict__ ssrc,
                          const float* __restrict__ sdst, const float* __restrict__ h,
                          const float* __restrict__ bias, float* __restrict__ out,
                          int n, int relu) {
    int wave = threadIdx.x >> 6;
    int lane = threadIdx.x & 63;
    int node = blockIdx.x * 4 + wave;
    if (node >= n) return;

    int start = row[node];
    int end = start + deg[node];
    float sd = sdst[node];
    float selfs = lrelu(ssrc[node] + sd);

    // pass 1: segment max (self-loop included)
    float mx = selfs;
    for (int j = start + lane; j < end; j += 64)
        mx = fmaxf(mx, lrelu(ssrc[csr[j]] + sd));
    mx = wave_max(mx);

    // pass 2: softmax-weighted gather; lane group g (of 4) covers edge c*4+g,
    // each lane loads float4 -> one wave instruction fetches 4 src rows.
    int group = lane >> 4;
    int fl4 = (lane & 15) * 4;
    float4 acc = {0.f, 0.f, 0.f, 0.f};
    float denomp = 0.f;
    float wself = __expf(selfs - mx);

    for (int base = start; base < end; base += 64) {
        int cnt = min(64, end - base);
        int sj = (lane < cnt) ? csr[base + lane] : 0;
        float wj = (lane < cnt) ? __expf(lrelu(ssrc[sj] + sd) - mx) : 0.f;
        denomp += wj;
        int nq = (cnt + 3) >> 2;
        // depth-2 software pipeline
        float w0 = __shfl(wj, group, 64);
        int s0 = __shfl(sj, group, 64);
        float4 hv0 = *(const float4*)&h[(size_t)s0 * ND + fl4];
        for (int c = 1; c < nq; c++) {
            float w1 = __shfl(wj, c * 4 + group, 64);
            int s1 = __shfl(sj, c * 4 + group, 64);
            float4 hv1 = *(const float4*)&h[(size_t)s1 * ND + fl4];
            acc.x = fmaf(w0, hv0.x, acc.x);
            acc.y = fmaf(w0, hv0.y, acc.y);
            acc.z = fmaf(w0, hv0.z, acc.z);
            acc.w = fmaf(w0, hv0.w, acc.w);
            w0 = w1; hv0 = hv1;
        }
        acc.x = fmaf(w0, hv0.x, acc.x);
        acc.y = fmaf(w0, hv0.y, acc.y);
        acc.z = fmaf(w0, hv0.z, acc.z);
        acc.w = fmaf(w0, hv0.w, acc.w);
    }

    // combine the 4 groups
#pragma unroll
    for (int m = 16; m < 64; m <<= 1) {
        acc.x += __shfl_xor(acc.x, m, 64);
        acc.y += __shfl_xor(acc.y, m, 64);
        acc.z += __shfl_xor(acc.z, m, 64);
        acc.w += __shfl_xor(acc.w, m, 64);
    }
    float denom = wave_sum(denomp) + wself;

    // self contribution + epilogue
    float4 hs = *(const float4*)&h[(size_t)node * ND + fl4];
    float4 bv = *(const float4*)&bias[fl4];
    float4 v;
    v.x = (acc.x + wself * hs.x) / denom + bv.x;
    v.y = (acc.y + wself * hs.y) / denom + bv.y;
    v.z = (acc.z + wself * hs.z) / denom + bv.z;
    v.w = (acc.w + wself * hs.w) / denom + bv.w;
    if (relu) {
        v.x = fmaxf(v.x, 0.f); v.y = fmaxf(v.y, 0.f);
        v.z = fmaxf(v.z, 0.f); v.w = fmaxf(v.w, 0.f);
    }
    if (group == 0) *(float4*)&out[(size_t)node * ND + fl4] = v;
}

// branch attention: fused = softmax2 blend (one wave per node)
__global__ void branch_att(const float* __restrict__ hi, const float* __restrict__ hp,
                           const float* __restrict__ att, float* __restrict__ fused, int n) {
    int gid = blockIdx.x * blockDim.x + threadIdx.x;
    int node = gid >> 6, lane = gid & 63;
    if (node >= n) return;
    float vi = hi[(size_t)node * ND + lane], vp = hp[(size_t)node * ND + lane];
    float s0 = wave_sum(att[lane] * vi);
    float s1 = wave_sum(att[ND + lane] * vp);
    float m = fmaxf(s0, s1);
    float a0 = __expf(s0 - m), a1 = __expf(s1 - m);
    fused[(size_t)node * ND + lane] = (a0 * vi + a1 * vp) / (a0 + a1);
}

// branch attention + final 64->1 MLP
__global__ void branch_att_mlp(const float* __restrict__ gi, const float* __restrict__ gp,
                               const float* __restrict__ att, const float* __restrict__ mlpw,
                               const float* __restrict__ mlpb, float* __restrict__ out, int n) {
    int gid = blockIdx.x * blockDim.x + threadIdx.x;
    int node = gid >> 6, lane = gid & 63;
    if (node >= n) return;
    float vi = gi[(size_t)node * ND + lane], vp = gp[(size_t)node * ND + lane];
    float s0 = wave_sum(att[lane] * vi);
    float s1 = wave_sum(att[ND + lane] * vp);
    float m = fmaxf(s0, s1);
    float a0 = __expf(s0 - m), a1 = __expf(s1 - m);
    float xj = (a0 * vi + a1 * vp) / (a0 + a1);
    float o = wave_sum(xj * mlpw[lane]);
    if (lane == 0) out[node] = o + mlpb[0];
}

extern "C" void kernel_launch(void* const* d_in, const int* in_sizes, int n_in,
                              void* d_out, int out_size, void* d_ws, size_t ws_size,
                              hipStream_t stream) {
    const int N = in_sizes[0] / ND;   // 50000
    const int E = in_sizes[2] / 2;    // 1600000

    const float* x_ind = (const float*)d_in[0];
    const float* x_pos = (const float*)d_in[1];
    const int*   e_ind = (const int*)d_in[2];
    const int*   e_pos = (const int*)d_in[3];
    const float* w1i = (const float*)d_in[4];
    const float* as1i = (const float*)d_in[5];
    const float* ad1i = (const float*)d_in[6];
    const float* b1i = (const float*)d_in[7];
    const float* w2i = (const float*)d_in[8];
    const float* as2i = (const float*)d_in[9];
    const float* ad2i = (const float*)d_in[10];
    const float* b2i = (const float*)d_in[11];
    const float* w1p = (const float*)d_in[12];
    const float* as1p = (const float*)d_in[13];
    const float* ad1p = (const float*)d_in[14];
    const float* b1p = (const float*)d_in[15];
    const float* w2p = (const float*)d_in[16];
    const float* as2p = (const float*)d_in[17];
    const float* ad2p = (const float*)d_in[18];
    const float* b2p = (const float*)d_in[19];
    const float* fha = (const float*)d_in[20];
    const float* attw = (const float*)d_in[21];
    const float* mlpw = (const float*)d_in[22];
    const float* mlpb = (const float*)d_in[23];

    char* ws = (char*)d_ws;
    size_t off = 0;
    auto alloc = [&](size_t elems) { void* p = ws + off; off += elems * 4; return p; };

    float* htmp = (float*)alloc((size_t)N * ND);
    float* bufA = (float*)alloc((size_t)N * ND);   // h_i then g_i
    float* bufB = (float*)alloc((size_t)N * ND);   // h_p then g_p
    float* bufC = (float*)alloc((size_t)N * ND);   // fused
    float* ssrc = (float*)alloc(N);
    float* sdst = (float*)alloc(N);
    int* deg    = (int*)alloc(2 * (size_t)N);
    int* rowi   = (int*)alloc(2 * (size_t)N);
    int* cursor = (int*)alloc(2 * (size_t)N);
    int* csr    = (int*)alloc(2 * (size_t)E);
    int* psum   = (int*)alloc(1024);

    const int n2 = 2 * N;
    const int nodeBlocks = (N + 3) / 4;            // aggregate / branch kernels
    const int gemmBlocks = (N + 15) / 16;          // gemm_scores (16 nodes/block)
    const int edge2Blocks = (2 * E + 255) / 256;
    const int nScanBlocks = (n2 + SCAN_BS - 1) / SCAN_BS;   // 391 <= 1024

    // ---- CSR build (both graphs) ----
    hipMemsetAsync(deg, 0, (size_t)n2 * 4, stream);
    hist2<<<edge2Blocks, 256, 0, stream>>>(e_ind, e_pos, deg, N, E);
    scan_blocks<<<nScanBlocks, SCAN_BS, 0, stream>>>(deg, rowi, psum, n2);
    scan_psum<<<1, 1024, 0, stream>>>(psum, nScanBlocks);
    scan_add<<<nScanBlocks, SCAN_BS, 0, stream>>>(rowi, cursor, psum, n2);
    scatter2<<<edge2Blocks, 256, 0, stream>>>(e_ind, e_pos, cursor, csr, N, E);

    auto conv = [&](const float* x, int graphOff, const float* W, const float* as,
                    const float* ad, const float* b, float* out, int relu) {
        gemm_scores<<<gemmBlocks, 256, 0, stream>>>(x, W, as, ad, htmp, ssrc, sdst, N);
        aggregate<<<nodeBlocks, 256, 0, stream>>>(csr, rowi + graphOff, deg + graphOff,
                                                  ssrc, sdst, htmp, b, out, N, relu);
    };

    conv(x_ind, 0, w1i, as1i, ad1i, b1i, bufA, 1);
    conv(x_pos, N, w1p, as1p, ad1p, b1p, bufB, 1);
    branch_att<<<nodeBlocks, 256, 0, stream>>>(bufA, bufB, fha, bufC, N);
    conv(bufC, 0, w2i, as2i, ad2i, b2i, bufA, 0);
    conv(bufC, N, w2p, as2p, ad2p, b2p, bufB, 0);
    branch_att_mlp<<<nodeBlocks, 256, 0, stream>>>(bufA, bufB, attw, mlpw, mlpb,
                                                   (float*)d_out, N);
}

// Round 4
// 557.679 us; speedup vs baseline: 4.1821x; 1.5565x over previous
//
#include <hip/hip_runtime.h>

#define ND 64
#define BG 256        // dst ids per bucket
#define MAXB 512      // max buckets (LDS sizing); nb = ceil(2N/BG) = 391
#define PCH 4096      // edges per partition-block chunk

__device__ __forceinline__ float lrelu(float x) { return x > 0.f ? x : 0.2f * x; }

__device__ __forceinline__ float wave_sum(float v) {
#pragma unroll
    for (int m = 32; m > 0; m >>= 1) v += __shfl_xor(v, m, 64);
    return v;
}
__device__ __forceinline__ float wave_max(float v) {
#pragma unroll
    for (int m = 32; m > 0; m >>= 1) v = fmaxf(v, __shfl_xor(v, m, 64));
    return v;
}

// ---------------- bucketed CSR build ----------------
// combined dst index idx = graph*N + dst in [0, n2); bucket = idx >> 8.

__global__ void bucket_count(const int* __restrict__ eI, const int* __restrict__ eP,
                             int* __restrict__ bcount, int N, int E, int nb) {
    __shared__ int hist[MAXB];
    for (int b = threadIdx.x; b < nb; b += blockDim.x) hist[b] = 0;
    __syncthreads();
    int total = 2 * E;
    for (int e = blockIdx.x * blockDim.x + threadIdx.x; e < total;
         e += gridDim.x * blockDim.x) {
        int idx = (e < E) ? eI[E + e] : N + eP[E + (e - E)];
        atomicAdd(&hist[idx >> 8], 1);
    }
    __syncthreads();
    for (int b = threadIdx.x; b < nb; b += blockDim.x)
        if (hist[b]) atomicAdd(&bcount[b], hist[b]);
}

__global__ void bucket_scan(const int* __restrict__ bcount, int* __restrict__ bstart,
                            int* __restrict__ bcursor, int nb) {
    __shared__ int tmp[512];
    int t = threadIdx.x;
    int v = (t < nb) ? bcount[t] : 0;
    tmp[t] = v;
    __syncthreads();
    for (int off = 1; off < 512; off <<= 1) {
        int a = (t >= off) ? tmp[t - off] : 0;
        __syncthreads();
        tmp[t] += a;
        __syncthreads();
    }
    if (t < nb) { int s = tmp[t] - v; bstart[t] = s; bcursor[t] = s; }
}

// multi-split: each block partitions a 4096-edge chunk into reserved per-bucket runs
__global__ void partition(const int* __restrict__ eI, const int* __restrict__ eP,
                          int* __restrict__ bcursor, int2* __restrict__ part,
                          int N, int E, int nb) {
    __shared__ int hist[MAXB];
    __shared__ int lcur[MAXB];
    int t = threadIdx.x;
    int total = 2 * E;
    int chunkBase = blockIdx.x * PCH;
    int cnt = min(PCH, total - chunkBase);
    for (int b = t; b < nb; b += 256) hist[b] = 0;
    __syncthreads();
    for (int i = t; i < cnt; i += 256) {
        int e = chunkBase + i;
        int idx = (e < E) ? eI[E + e] : N + eP[E + (e - E)];
        atomicAdd(&hist[idx >> 8], 1);
    }
    __syncthreads();
    for (int b = t; b < nb; b += 256)
        lcur[b] = hist[b] ? atomicAdd(&bcursor[b], hist[b]) : 0;
    __syncthreads();
    for (int i = t; i < cnt; i += 256) {
        int e = chunkBase + i;
        int s, idx;
        if (e < E) { s = eI[e]; idx = eI[E + e]; }
        else       { s = eP[e - E]; idx = N + eP[E + (e - E)]; }
        int pos = atomicAdd(&lcur[idx >> 8], 1);
        part[pos] = make_int2(s, idx);
    }
}

// one block per bucket: per-dst hist + scan -> row/deg, then LDS-cursor scatter
// into an XCD-local ~33 KB csr window. blockDim must be 256 (== BG).
__global__ void bucket_build(const int2* __restrict__ part, const int* __restrict__ bstart,
                             const int* __restrict__ bcount, int* __restrict__ row,
                             int* __restrict__ deg, int* __restrict__ csr, int n2) {
    __shared__ int lhist[BG];
    __shared__ int lrow[BG];
    int b = blockIdx.x, t = threadIdx.x;
    int start = bstart[b], cnt = bcount[b];
    lhist[t] = 0;
    __syncthreads();
    for (int j = t; j < cnt; j += 256) atomicAdd(&lhist[part[start + j].y & (BG - 1)], 1);
    __syncthreads();
    int v = lhist[t];
    lrow[t] = v;
    __syncthreads();
    for (int off = 1; off < 256; off <<= 1) {
        int a = (t >= off) ? lrow[t - off] : 0;
        __syncthreads();
        lrow[t] += a;
        __syncthreads();
    }
    int excl = lrow[t] - v;
    int g = b * BG + t;
    if (g < n2) { row[g] = start + excl; deg[g] = v; }
    __syncthreads();
    lhist[t] = start + excl;          // reuse as global write cursor
    __syncthreads();
    for (int j = t; j < cnt; j += 256) {
        int2 p = part[start + j];
        int pos = atomicAdd(&lhist[p.y & (BG - 1)], 1);
        csr[pos] = p.x;
    }
}

// ---------------- h = x @ W + score dots: 4 nodes per wave ----------------
__global__ void gemm_scores(const float* __restrict__ x, const float* __restrict__ W,
                            const float* __restrict__ asrc, const float* __restrict__ adst,
                            float* __restrict__ h, float* __restrict__ ssrc,
                            float* __restrict__ sdst, int n) {
    int wave = threadIdx.x >> 6;
    int lane = threadIdx.x & 63;
    int nodeBase = (blockIdx.x * 4 + wave) * 4;
    __shared__ float xs[4][4 * ND];

    if (nodeBase + 3 < n) {
        *(float4*)&xs[wave][lane * 4] = *(const float4*)&x[(size_t)nodeBase * ND + lane * 4];
    } else {
#pragma unroll
        for (int i = 0; i < 4; i++) {
            int gi = nodeBase * ND + lane * 4 + i;
            xs[wave][lane * 4 + i] = (gi < n * ND) ? x[gi] : 0.f;
        }
    }
    __syncthreads();
    if (nodeBase >= n) return;

    float4 acc = {0.f, 0.f, 0.f, 0.f};
#pragma unroll
    for (int k = 0; k < ND; k++) {
        float wv = W[k * ND + lane];
        acc.x = fmaf(xs[wave][0 * ND + k], wv, acc.x);
        acc.y = fmaf(xs[wave][1 * ND + k], wv, acc.y);
        acc.z = fmaf(xs[wave][2 * ND + k], wv, acc.z);
        acc.w = fmaf(xs[wave][3 * ND + k], wv, acc.w);
    }
    float av = asrc[lane], dv = adst[lane];
    float s1x = wave_sum(acc.x * av), s2x = wave_sum(acc.x * dv);
    float s1y = wave_sum(acc.y * av), s2y = wave_sum(acc.y * dv);
    float s1z = wave_sum(acc.z * av), s2z = wave_sum(acc.z * dv);
    float s1w = wave_sum(acc.w * av), s2w = wave_sum(acc.w * dv);

    h[(size_t)(nodeBase + 0) * ND + lane] = acc.x;
    if (nodeBase + 1 < n) h[(size_t)(nodeBase + 1) * ND + lane] = acc.y;
    if (nodeBase + 2 < n) h[(size_t)(nodeBase + 2) * ND + lane] = acc.z;
    if (nodeBase + 3 < n) h[(size_t)(nodeBase + 3) * ND + lane] = acc.w;
    if (lane == 0) {
        ssrc[nodeBase] = s1x; sdst[nodeBase] = s2x;
        if (nodeBase + 1 < n) { ssrc[nodeBase + 1] = s1y; sdst[nodeBase + 1] = s2y; }
        if (nodeBase + 2 < n) { ssrc[nodeBase + 2] = s1z; sdst[nodeBase + 2] = s2z; }
        if (nodeBase + 3 < n) { ssrc[nodeBase + 3] = s1w; sdst[nodeBase + 3] = s2w; }
    }
}

// ---------------- aggregate: one wave per dst, 4-row float4 gathers ----------------
__global__ void aggregate(const int* __restrict__ csr, const int* __restrict__ row,
                          const int* __restrict__ deg, const float* __restrict__ ssrc,
                          const float* __restrict__ sdst, const float* __restrict__ h,
                          const float* __restrict__ bias, float* __restrict__ out,
                          int n, int relu) {
    int wave = threadIdx.x >> 6;
    int lane = threadIdx.x & 63;
    int node = blockIdx.x * 4 + wave;
    if (node >= n) return;

    int start = row[node];
    int end = start + deg[node];
    float sd = sdst[node];
    float selfs = lrelu(ssrc[node] + sd);

    float mx = selfs;
    for (int j = start + lane; j < end; j += 64)
        mx = fmaxf(mx, lrelu(ssrc[csr[j]] + sd));
    mx = wave_max(mx);

    int group = lane >> 4;
    int fl4 = (lane & 15) * 4;
    float4 acc = {0.f, 0.f, 0.f, 0.f};
    float denomp = 0.f;
    float wself = __expf(selfs - mx);

    for (int base = start; base < end; base += 64) {
        int cnt = min(64, end - base);
        int sj = (lane < cnt) ? csr[base + lane] : 0;
        float wj = (lane < cnt) ? __expf(lrelu(ssrc[sj] + sd) - mx) : 0.f;
        denomp += wj;
        int nq = (cnt + 3) >> 2;
        float w0 = __shfl(wj, group, 64);
        int s0 = __shfl(sj, group, 64);
        float4 hv0 = *(const float4*)&h[(size_t)s0 * ND + fl4];
        for (int c = 1; c < nq; c++) {
            float w1 = __shfl(wj, c * 4 + group, 64);
            int s1 = __shfl(sj, c * 4 + group, 64);
            float4 hv1 = *(const float4*)&h[(size_t)s1 * ND + fl4];
            acc.x = fmaf(w0, hv0.x, acc.x);
            acc.y = fmaf(w0, hv0.y, acc.y);
            acc.z = fmaf(w0, hv0.z, acc.z);
            acc.w = fmaf(w0, hv0.w, acc.w);
            w0 = w1; hv0 = hv1;
        }
        acc.x = fmaf(w0, hv0.x, acc.x);
        acc.y = fmaf(w0, hv0.y, acc.y);
        acc.z = fmaf(w0, hv0.z, acc.z);
        acc.w = fmaf(w0, hv0.w, acc.w);
    }

#pragma unroll
    for (int m = 16; m < 64; m <<= 1) {
        acc.x += __shfl_xor(acc.x, m, 64);
        acc.y += __shfl_xor(acc.y, m, 64);
        acc.z += __shfl_xor(acc.z, m, 64);
        acc.w += __shfl_xor(acc.w, m, 64);
    }
    float denom = wave_sum(denomp) + wself;

    float4 hs = *(const float4*)&h[(size_t)node * ND + fl4];
    float4 bv = *(const float4*)&bias[fl4];
    float4 v;
    v.x = (acc.x + wself * hs.x) / denom + bv.x;
    v.y = (acc.y + wself * hs.y) / denom + bv.y;
    v.z = (acc.z + wself * hs.z) / denom + bv.z;
    v.w = (acc.w + wself * hs.w) / denom + bv.w;
    if (relu) {
        v.x = fmaxf(v.x, 0.f); v.y = fmaxf(v.y, 0.f);
        v.z = fmaxf(v.z, 0.f); v.w = fmaxf(v.w, 0.f);
    }
    if (group == 0) *(float4*)&out[(size_t)node * ND + fl4] = v;
}

// branch attention: fused = softmax2 blend (one wave per node)
__global__ void branch_att(const float* __restrict__ hi, const float* __restrict__ hp,
                           const float* __restrict__ att, float* __restrict__ fused, int n) {
    int gid = blockIdx.x * blockDim.x + threadIdx.x;
    int node = gid >> 6, lane = gid & 63;
    if (node >= n) return;
    float vi = hi[(size_t)node * ND + lane], vp = hp[(size_t)node * ND + lane];
    float s0 = wave_sum(att[lane] * vi);
    float s1 = wave_sum(att[ND + lane] * vp);
    float m = fmaxf(s0, s1);
    float a0 = __expf(s0 - m), a1 = __expf(s1 - m);
    fused[(size_t)node * ND + lane] = (a0 * vi + a1 * vp) / (a0 + a1);
}

// branch attention + final 64->1 MLP
__global__ void branch_att_mlp(const float* __restrict__ gi, const float* __restrict__ gp,
                               const float* __restrict__ att, const float* __restrict__ mlpw,
                               const float* __restrict__ mlpb, float* __restrict__ out, int n) {
    int gid = blockIdx.x * blockDim.x + threadIdx.x;
    int node = gid >> 6, lane = gid & 63;
    if (node >= n) return;
    float vi = gi[(size_t)node * ND + lane], vp = gp[(size_t)node * ND + lane];
    float s0 = wave_sum(att[lane] * vi);
    float s1 = wave_sum(att[ND + lane] * vp);
    float m = fmaxf(s0, s1);
    float a0 = __expf(s0 - m), a1 = __expf(s1 - m);
    float xj = (a0 * vi + a1 * vp) / (a0 + a1);
    float o = wave_sum(xj * mlpw[lane]);
    if (lane == 0) out[node] = o + mlpb[0];
}

extern "C" void kernel_launch(void* const* d_in, const int* in_sizes, int n_in,
                              void* d_out, int out_size, void* d_ws, size_t ws_size,
                              hipStream_t stream) {
    const int N = in_sizes[0] / ND;   // 50000
    const int E = in_sizes[2] / 2;    // 1600000

    const float* x_ind = (const float*)d_in[0];
    const float* x_pos = (const float*)d_in[1];
    const int*   e_ind = (const int*)d_in[2];
    const int*   e_pos = (const int*)d_in[3];
    const float* w1i = (const float*)d_in[4];
    const float* as1i = (const float*)d_in[5];
    const float* ad1i = (const float*)d_in[6];
    const float* b1i = (const float*)d_in[7];
    const float* w2i = (const float*)d_in[8];
    const float* as2i = (const float*)d_in[9];
    const float* ad2i = (const float*)d_in[10];
    const float* b2i = (const float*)d_in[11];
    const float* w1p = (const float*)d_in[12];
    const float* as1p = (const float*)d_in[13];
    const float* ad1p = (const float*)d_in[14];
    const float* b1p = (const float*)d_in[15];
    const float* w2p = (const float*)d_in[16];
    const float* as2p = (const float*)d_in[17];
    const float* ad2p = (const float*)d_in[18];
    const float* b2p = (const float*)d_in[19];
    const float* fha = (const float*)d_in[20];
    const float* attw = (const float*)d_in[21];
    const float* mlpw = (const float*)d_in[22];
    const float* mlpb = (const float*)d_in[23];

    char* ws = (char*)d_ws;
    size_t off = 0;
    auto alloc = [&](size_t elems) { void* p = ws + off; off += elems * 4; return p; };

    float* htmp = (float*)alloc((size_t)N * ND);
    float* bufA = (float*)alloc((size_t)N * ND);   // h_i then g_i
    float* bufB = (float*)alloc((size_t)N * ND);   // h_p then g_p
    float* bufC = (float*)alloc((size_t)N * ND);   // fused
    float* ssrc = (float*)alloc(N);
    float* sdst = (float*)alloc(N);
    int* deg    = (int*)alloc(2 * (size_t)N);
    int* rowi   = (int*)alloc(2 * (size_t)N);
    int* csr    = (int*)alloc(2 * (size_t)E);
    int* bcount = (int*)alloc(MAXB);
    int* bstart = (int*)alloc(MAXB);
    int* bcursor= (int*)alloc(MAXB);
    // part[2E] int2 aliases htmp+bufA (consumed before any conv writes them)
    int2* part  = (int2*)htmp;

    const int n2 = 2 * N;
    const int nb = (n2 + BG - 1) / BG;             // 391
    const int nodeBlocks = (N + 3) / 4;
    const int gemmBlocks = (N + 15) / 16;
    const int partBlocks = (2 * E + PCH - 1) / PCH;

    // ---- bucketed CSR build (both graphs, no global hist/scan) ----
    hipMemsetAsync(bcount, 0, (size_t)nb * 4, stream);
    bucket_count<<<512, 256, 0, stream>>>(e_ind, e_pos, bcount, N, E, nb);
    bucket_scan<<<1, 512, 0, stream>>>(bcount, bstart, bcursor, nb);
    partition<<<partBlocks, 256, 0, stream>>>(e_ind, e_pos, bcursor, part, N, E, nb);
    bucket_build<<<nb, 256, 0, stream>>>(part, bstart, bcount, rowi, deg, csr, n2);

    auto conv = [&](const float* x, int graphOff, const float* W, const float* as,
                    const float* ad, const float* b, float* out, int relu) {
        gemm_scores<<<gemmBlocks, 256, 0, stream>>>(x, W, as, ad, htmp, ssrc, sdst, N);
        aggregate<<<nodeBlocks, 256, 0, stream>>>(csr, rowi + graphOff, deg + graphOff,
                                                  ssrc, sdst, htmp, b, out, N, relu);
    };

    conv(x_ind, 0, w1i, as1i, ad1i, b1i, bufA, 1);
    conv(x_pos, N, w1p, as1p, ad1p, b1p, bufB, 1);
    branch_att<<<nodeBlocks, 256, 0, stream>>>(bufA, bufB, fha, bufC, N);
    conv(bufC, 0, w2i, as2i, ad2i, b2i, bufA, 0);
    conv(bufC, N, w2p, as2p, ad2p, b2p, bufB, 0);
    branch_att_mlp<<<nodeBlocks, 256, 0, stream>>>(bufA, bufB, attw, mlpw, mlpb,
                                                   (float*)d_out, N);
}

// Round 5
// 447.236 us; speedup vs baseline: 5.2149x; 1.2469x over previous
//
#include <hip/hip_runtime.h>
#include <hip/hip_fp16.h>

#define ND 64
#define BG 256        // dst ids per bucket
#define MAXB 512      // max buckets (LDS sizing); nb = ceil(2N/BG) = 391
#define PCH 8192      // edges per partition-block chunk

__device__ __forceinline__ float lrelu(float x) { return x > 0.f ? x : 0.2f * x; }

__device__ __forceinline__ float wave_sum(float v) {
#pragma unroll
    for (int m = 32; m > 0; m >>= 1) v += __shfl_xor(v, m, 64);
    return v;
}

// 8 halves (int4 raw) fused into 8 fp32 accumulators
__device__ __forceinline__ void fma8(float* acc, float w, int4 raw) {
    union { int4 i; __half2 h[4]; } u;
    u.i = raw;
#pragma unroll
    for (int i = 0; i < 4; i++) {
        float2 f = __half22float2(u.h[i]);
        acc[2 * i]     = fmaf(w, f.x, acc[2 * i]);
        acc[2 * i + 1] = fmaf(w, f.y, acc[2 * i + 1]);
    }
}

// ---------------- bucketed CSR build ----------------
// combined dst index idx = graph*N + dst in [0, n2); bucket = idx >> 8.

__global__ void bucket_count(const int* __restrict__ eI, const int* __restrict__ eP,
                             int* __restrict__ bcount, int N, int E, int nb) {
    __shared__ int hist[MAXB];
    for (int b = threadIdx.x; b < nb; b += blockDim.x) hist[b] = 0;
    __syncthreads();
    int total = 2 * E;
    for (int e = blockIdx.x * blockDim.x + threadIdx.x; e < total;
         e += gridDim.x * blockDim.x) {
        int idx = (e < E) ? eI[E + e] : N + eP[E + (e - E)];
        atomicAdd(&hist[idx >> 8], 1);
    }
    __syncthreads();
    for (int b = threadIdx.x; b < nb; b += blockDim.x)
        if (hist[b]) atomicAdd(&bcount[b], hist[b]);
}

__global__ void bucket_scan(const int* __restrict__ bcount, int* __restrict__ bstart,
                            int* __restrict__ bcursor, int nb) {
    __shared__ int tmp[512];
    int t = threadIdx.x;
    int v = (t < nb) ? bcount[t] : 0;
    tmp[t] = v;
    __syncthreads();
    for (int off = 1; off < 512; off <<= 1) {
        int a = (t >= off) ? tmp[t - off] : 0;
        __syncthreads();
        tmp[t] += a;
        __syncthreads();
    }
    if (t < nb) { int s = tmp[t] - v; bstart[t] = s; bcursor[t] = s; }
}

// multi-split into reserved per-bucket runs; entry packed (src<<8 | idx&255)
__global__ void partition(const int* __restrict__ eI, const int* __restrict__ eP,
                          int* __restrict__ bcursor, int* __restrict__ part,
                          int N, int E, int nb) {
    __shared__ int hist[MAXB];
    __shared__ int lcur[MAXB];
    int t = threadIdx.x;
    int total = 2 * E;
    int chunkBase = blockIdx.x * PCH;
    int cnt = min(PCH, total - chunkBase);
    for (int b = t; b < nb; b += 256) hist[b] = 0;
    __syncthreads();
    for (int i = t; i < cnt; i += 256) {
        int e = chunkBase + i;
        int idx = (e < E) ? eI[E + e] : N + eP[E + (e - E)];
        atomicAdd(&hist[idx >> 8], 1);
    }
    __syncthreads();
    for (int b = t; b < nb; b += 256)
        lcur[b] = hist[b] ? atomicAdd(&bcursor[b], hist[b]) : 0;
    __syncthreads();
    for (int i = t; i < cnt; i += 256) {
        int e = chunkBase + i;
        int s, idx;
        if (e < E) { s = eI[e]; idx = eI[E + e]; }
        else       { s = eP[e - E]; idx = N + eP[E + (e - E)]; }
        int pos = atomicAdd(&lcur[idx >> 8], 1);
        part[pos] = (s << 8) | (idx & (BG - 1));
    }
}

// one block per bucket: per-dst hist + scan -> row/deg, LDS-cursor scatter of src
__global__ void bucket_build(const int* __restrict__ part, const int* __restrict__ bstart,
                             const int* __restrict__ bcount, int* __restrict__ row,
                             int* __restrict__ deg, int* __restrict__ csr, int n2) {
    __shared__ int lhist[BG];
    __shared__ int lrow[BG];
    int b = blockIdx.x, t = threadIdx.x;
    int start = bstart[b], cnt = bcount[b];
    lhist[t] = 0;
    __syncthreads();
    for (int j = t; j < cnt; j += 256) atomicAdd(&lhist[part[start + j] & (BG - 1)], 1);
    __syncthreads();
    int v = lhist[t];
    lrow[t] = v;
    __syncthreads();
    for (int off = 1; off < 256; off <<= 1) {
        int a = (t >= off) ? lrow[t - off] : 0;
        __syncthreads();
        lrow[t] += a;
        __syncthreads();
    }
    int excl = lrow[t] - v;
    int g = b * BG + t;
    if (g < n2) { row[g] = start + excl; deg[g] = v; }
    __syncthreads();
    lhist[t] = start + excl;          // reuse as global write cursor
    __syncthreads();
    for (int j = t; j < cnt; j += 256) {
        int p = part[start + j];
        int pos = atomicAdd(&lhist[p & (BG - 1)], 1);
        csr[pos] = p >> 8;
    }
}

// ---------------- h(fp16) = x @ W + score dots: 4 nodes per wave ----------------
__global__ void gemm_scores(const float* __restrict__ x, const float* __restrict__ W,
                            const float* __restrict__ asrc, const float* __restrict__ adst,
                            __half* __restrict__ h16, float* __restrict__ ssrc,
                            float* __restrict__ sdst, int n) {
    int wave = threadIdx.x >> 6;
    int lane = threadIdx.x & 63;
    int nodeBase = (blockIdx.x * 4 + wave) * 4;
    __shared__ float xs[4][4 * ND];

    if (nodeBase + 3 < n) {
        *(float4*)&xs[wave][lane * 4] = *(const float4*)&x[(size_t)nodeBase * ND + lane * 4];
    } else {
#pragma unroll
        for (int i = 0; i < 4; i++) {
            int gi = nodeBase * ND + lane * 4 + i;
            xs[wave][lane * 4 + i] = (gi < n * ND) ? x[gi] : 0.f;
        }
    }
    __syncthreads();
    if (nodeBase >= n) return;

    float4 acc = {0.f, 0.f, 0.f, 0.f};
#pragma unroll
    for (int k = 0; k < ND; k++) {
        float wv = W[k * ND + lane];
        acc.x = fmaf(xs[wave][0 * ND + k], wv, acc.x);
        acc.y = fmaf(xs[wave][1 * ND + k], wv, acc.y);
        acc.z = fmaf(xs[wave][2 * ND + k], wv, acc.z);
        acc.w = fmaf(xs[wave][3 * ND + k], wv, acc.w);
    }
    float av = asrc[lane], dv = adst[lane];
    float s1x = wave_sum(acc.x * av), s2x = wave_sum(acc.x * dv);
    float s1y = wave_sum(acc.y * av), s2y = wave_sum(acc.y * dv);
    float s1z = wave_sum(acc.z * av), s2z = wave_sum(acc.z * dv);
    float s1w = wave_sum(acc.w * av), s2w = wave_sum(acc.w * dv);

    h16[(size_t)(nodeBase + 0) * ND + lane] = __float2half(acc.x);
    if (nodeBase + 1 < n) h16[(size_t)(nodeBase + 1) * ND + lane] = __float2half(acc.y);
    if (nodeBase + 2 < n) h16[(size_t)(nodeBase + 2) * ND + lane] = __float2half(acc.z);
    if (nodeBase + 3 < n) h16[(size_t)(nodeBase + 3) * ND + lane] = __float2half(acc.w);
    if (lane == 0) {
        ssrc[nodeBase] = s1x; sdst[nodeBase] = s2x;
        if (nodeBase + 1 < n) { ssrc[nodeBase + 1] = s1y; sdst[nodeBase + 1] = s2y; }
        if (nodeBase + 2 < n) { ssrc[nodeBase + 2] = s1z; sdst[nodeBase + 2] = s2z; }
        if (nodeBase + 3 < n) { ssrc[nodeBase + 3] = s1w; sdst[nodeBase + 3] = s2w; }
    }
}

// ---------------- aggregate: one wave per dst, single pass (no max shift),
// 8 lane-groups x int4(8 halves) -> one wave instr gathers 8 src rows ----------------
__global__ void aggregate(const int* __restrict__ csr, const int* __restrict__ row,
                          const int* __restrict__ deg, const float* __restrict__ ssrc,
                          const float* __restrict__ sdst, const __half* __restrict__ h16,
                          const float* __restrict__ bias, float* __restrict__ out,
                          int n, int relu) {
    int wave = threadIdx.x >> 6;
    int lane = threadIdx.x & 63;
    int node = blockIdx.x * 4 + wave;
    if (node >= n) return;

    int start = row[node];
    int end = start + deg[node];
    float sd = sdst[node];
    float wself = __expf(lrelu(ssrc[node] + sd));   // scores O(<=16): no overflow

    int group = lane >> 3;            // 8 groups of 8 lanes
    int fl8 = (lane & 7) * 8;         // 8 halves per lane
    float acc[8] = {0.f, 0.f, 0.f, 0.f, 0.f, 0.f, 0.f, 0.f};
    float denomp = 0.f;

    for (int base = start; base < end; base += 64) {
        int cnt = min(64, end - base);
        int sj = (lane < cnt) ? csr[base + lane] : 0;
        float wj = (lane < cnt) ? __expf(lrelu(ssrc[sj] + sd)) : 0.f;
        denomp += wj;
        int nq = (cnt + 7) >> 3;
        // depth-2 software pipeline over 8-edge steps
        float w0 = __shfl(wj, group, 64);
        int s0 = __shfl(sj, group, 64);
        int4 raw0 = *(const int4*)(h16 + (size_t)s0 * ND + fl8);
        for (int c = 1; c < nq; c++) {
            float w1 = __shfl(wj, c * 8 + group, 64);
            int s1 = __shfl(sj, c * 8 + group, 64);
            int4 raw1 = *(const int4*)(h16 + (size_t)s1 * ND + fl8);
            fma8(acc, w0, raw0);
            w0 = w1; raw0 = raw1;
        }
        fma8(acc, w0, raw0);
    }

    // combine the 8 groups
#pragma unroll
    for (int m = 8; m < 64; m <<= 1) {
#pragma unroll
        for (int i = 0; i < 8; i++) acc[i] += __shfl_xor(acc[i], m, 64);
    }
    float denom = wave_sum(denomp) + wself;

    // self contribution + epilogue (lanes 0..7 each own 8 outputs)
    int4 rawS = *(const int4*)(h16 + (size_t)node * ND + fl8);
    union { int4 i; __half2 h[4]; } us;
    us.i = rawS;
    float v[8];
#pragma unroll
    for (int i = 0; i < 4; i++) {
        float2 f = __half22float2(us.h[i]);
        v[2 * i]     = (acc[2 * i]     + wself * f.x) / denom + bias[fl8 + 2 * i];
        v[2 * i + 1] = (acc[2 * i + 1] + wself * f.y) / denom + bias[fl8 + 2 * i + 1];
    }
    if (relu) {
#pragma unroll
        for (int i = 0; i < 8; i++) v[i] = fmaxf(v[i], 0.f);
    }
    if (lane < 8) {
        *(float4*)&out[(size_t)node * ND + fl8]     = make_float4(v[0], v[1], v[2], v[3]);
        *(float4*)&out[(size_t)node * ND + fl8 + 4] = make_float4(v[4], v[5], v[6], v[7]);
    }
}

// branch attention: fused = softmax2 blend (one wave per node)
__global__ void branch_att(const float* __restrict__ hi, const float* __restrict__ hp,
                           const float* __restrict__ att, float* __restrict__ fused, int n) {
    int gid = blockIdx.x * blockDim.x + threadIdx.x;
    int node = gid >> 6, lane = gid & 63;
    if (node >= n) return;
    float vi = hi[(size_t)node * ND + lane], vp = hp[(size_t)node * ND + lane];
    float s0 = wave_sum(att[lane] * vi);
    float s1 = wave_sum(att[ND + lane] * vp);
    float m = fmaxf(s0, s1);
    float a0 = __expf(s0 - m), a1 = __expf(s1 - m);
    fused[(size_t)node * ND + lane] = (a0 * vi + a1 * vp) / (a0 + a1);
}

// branch attention + final 64->1 MLP
__global__ void branch_att_mlp(const float* __restrict__ gi, const float* __restrict__ gp,
                               const float* __restrict__ att, const float* __restrict__ mlpw,
                               const float* __restrict__ mlpb, float* __restrict__ out, int n) {
    int gid = blockIdx.x * blockDim.x + threadIdx.x;
    int node = gid >> 6, lane = gid & 63;
    if (node >= n) return;
    float vi = gi[(size_t)node * ND + lane], vp = gp[(size_t)node * ND + lane];
    float s0 = wave_sum(att[lane] * vi);
    float s1 = wave_sum(att[ND + lane] * vp);
    float m = fmaxf(s0, s1);
    float a0 = __expf(s0 - m), a1 = __expf(s1 - m);
    float xj = (a0 * vi + a1 * vp) / (a0 + a1);
    float o = wave_sum(xj * mlpw[lane]);
    if (lane == 0) out[node] = o + mlpb[0];
}

extern "C" void kernel_launch(void* const* d_in, const int* in_sizes, int n_in,
                              void* d_out, int out_size, void* d_ws, size_t ws_size,
                              hipStream_t stream) {
    const int N = in_sizes[0] / ND;   // 50000
    const int E = in_sizes[2] / 2;    // 1600000

    const float* x_ind = (const float*)d_in[0];
    const float* x_pos = (const float*)d_in[1];
    const int*   e_ind = (const int*)d_in[2];
    const int*   e_pos = (const int*)d_in[3];
    const float* w1i = (const float*)d_in[4];
    const float* as1i = (const float*)d_in[5];
    const float* ad1i = (const float*)d_in[6];
    const float* b1i = (const float*)d_in[7];
    const float* w2i = (const float*)d_in[8];
    const float* as2i = (const float*)d_in[9];
    const float* ad2i = (const float*)d_in[10];
    const float* b2i = (const float*)d_in[11];
    const float* w1p = (const float*)d_in[12];
    const float* as1p = (const float*)d_in[13];
    const float* ad1p = (const float*)d_in[14];
    const float* b1p = (const float*)d_in[15];
    const float* w2p = (const float*)d_in[16];
    const float* as2p = (const float*)d_in[17];
    const float* ad2p = (const float*)d_in[18];
    const float* b2p = (const float*)d_in[19];
    const float* fha = (const float*)d_in[20];
    const float* attw = (const float*)d_in[21];
    const float* mlpw = (const float*)d_in[22];
    const float* mlpb = (const float*)d_in[23];

    char* ws = (char*)d_ws;
    size_t off = 0;
    auto alloc = [&](size_t elems) { void* p = ws + off; off += elems * 4; return p; };

    __half* h16 = (__half*)alloc((size_t)N * ND / 2);   // fp16 features, 6.4 MB
    float* bufA = (float*)alloc((size_t)N * ND);        // h_i then g_i
    float* bufB = (float*)alloc((size_t)N * ND);        // h_p then g_p
    float* bufC = (float*)alloc((size_t)N * ND);        // fused
    float* ssrc = (float*)alloc(N);
    float* sdst = (float*)alloc(N);
    int* deg    = (int*)alloc(2 * (size_t)N);
    int* rowi   = (int*)alloc(2 * (size_t)N);
    int* csr    = (int*)alloc(2 * (size_t)E);
    int* bcount = (int*)alloc(MAXB);
    int* bstart = (int*)alloc(MAXB);
    int* bcursor= (int*)alloc(MAXB);
    // part[2E] ints alias bufA (12.8 MB) — consumed by bucket_build before conv-1
    int* part   = (int*)bufA;

    const int n2 = 2 * N;
    const int nb = (n2 + BG - 1) / BG;             // 391
    const int nodeBlocks = (N + 3) / 4;
    const int gemmBlocks = (N + 15) / 16;
    const int partBlocks = (2 * E + PCH - 1) / PCH;

    // ---- bucketed CSR build (both graphs) ----
    hipMemsetAsync(bcount, 0, (size_t)nb * 4, stream);
    bucket_count<<<512, 256, 0, stream>>>(e_ind, e_pos, bcount, N, E, nb);
    bucket_scan<<<1, 512, 0, stream>>>(bcount, bstart, bcursor, nb);
    partition<<<partBlocks, 256, 0, stream>>>(e_ind, e_pos, bcursor, part, N, E, nb);
    bucket_build<<<nb, 256, 0, stream>>>(part, bstart, bcount, rowi, deg, csr, n2);

    auto conv = [&](const float* x, int graphOff, const float* W, const float* as,
                    const float* ad, const float* b, float* out, int relu) {
        gemm_scores<<<gemmBlocks, 256, 0, stream>>>(x, W, as, ad, h16, ssrc, sdst, N);
        aggregate<<<nodeBlocks, 256, 0, stream>>>(csr, rowi + graphOff, deg + graphOff,
                                                  ssrc, sdst, h16, b, out, N, relu);
    };

    conv(x_ind, 0, w1i, as1i, ad1i, b1i, bufA, 1);
    conv(x_pos, N, w1p, as1p, ad1p, b1p, bufB, 1);
    branch_att<<<nodeBlocks, 256, 0, stream>>>(bufA, bufB, fha, bufC, N);
    conv(bufC, 0, w2i, as2i, ad2i, b2i, bufA, 0);
    conv(bufC, N, w2p, as2p, ad2p, b2p, bufB, 0);
    branch_att_mlp<<<nodeBlocks, 256, 0, stream>>>(bufA, bufB, attw, mlpw, mlpb,
                                                   (float*)d_out, N);
}